// Round 1
// baseline (836.644 us; speedup 1.0000x reference)
//
#include <hip/hip_runtime.h>
#include <hip/hip_bf16.h>
#include <cstdint>
#include <cstddef>

#define GS     128
#define OBS    1024
#define HSZ    256
#define OUTSZ  1024
#define NOUT   18
#define BATCH  256

// ---------------------------------------------------------------------------
// K1: Y[m][0:256]   = x_m @ W0_rel
//     Y[m][256:512] = x_m @ W0_root
// x_m = nodes[b,g,:] with row g==num_nodes[b] replaced by flat[b,:]
// M = B*GS = 32768, K = OBS = 1024, Ncat = 512.
// 64x64 block tile, 256 threads, 4x4 micro-tile, BK=16.
// ---------------------------------------------------------------------------
__global__ __launch_bounds__(256) void gemm0_kernel(
    const float* __restrict__ flat, const float* __restrict__ nodes,
    const int* __restrict__ num_nodes,
    const float* __restrict__ W0_rel, const float* __restrict__ W0_root,
    float* __restrict__ Y)
{
  __shared__ float As[16][64];   // [k][m]
  __shared__ float Bs[16][64];   // [k][n]

  const int n0 = blockIdx.x * 64;          // 0..448 (cat-column base)
  const int m0 = blockIdx.y * 64;          // row base; always within one batch
  const int b  = m0 >> 7;
  const int gbase = m0 & 127;
  const int nb = num_nodes[b];

  // weight base pointer for this column tile (tiles never straddle the 256 split)
  const float* W = (n0 < HSZ) ? (W0_rel + n0) : (W0_root + (n0 - HSZ));

  const int tid = threadIdx.x;
  const int tx = tid & 15;                 // micro col group
  const int ty = tid >> 4;                 // micro row group

  // A staging: thread -> (row, 4 k's)
  const int arow  = tid >> 2;              // 0..63
  const int acol4 = (tid & 3) * 4;         // 0,4,8,12
  const int g = gbase + arow;
  const float* xrow = (g == nb) ? (flat + (size_t)b * OBS)
                                : (nodes + ((size_t)b * GS + g) * OBS);
  // B staging: thread -> (k row, 4 n's)
  const int brow  = tid >> 4;              // 0..15
  const int bcol4 = (tid & 15) * 4;        // 0..60

  float acc[4][4] = {};

  for (int kk = 0; kk < OBS; kk += 16) {
    const float4 av = *(const float4*)(xrow + kk + acol4);
    const float4 bv = *(const float4*)(W + (size_t)(kk + brow) * HSZ + bcol4);
    As[acol4 + 0][arow] = av.x;
    As[acol4 + 1][arow] = av.y;
    As[acol4 + 2][arow] = av.z;
    As[acol4 + 3][arow] = av.w;
    *(float4*)&Bs[brow][bcol4] = bv;
    __syncthreads();
#pragma unroll
    for (int k = 0; k < 16; ++k) {
      const float4 a = *(const float4*)&As[k][ty * 4];
      const float4 q = *(const float4*)&Bs[k][tx * 4];
      const float af[4] = {a.x, a.y, a.z, a.w};
      const float qf[4] = {q.x, q.y, q.z, q.w};
#pragma unroll
      for (int i = 0; i < 4; ++i)
#pragma unroll
        for (int j = 0; j < 4; ++j)
          acc[i][j] = fmaf(af[i], qf[j], acc[i][j]);
    }
    __syncthreads();
  }

#pragma unroll
  for (int i = 0; i < 4; ++i) {
    float4 st;
    st.x = acc[i][0]; st.y = acc[i][1]; st.z = acc[i][2]; st.w = acc[i][3];
    *(float4*)&Y[(size_t)(m0 + ty * 4 + i) * 512 + n0 + tx * 4] = st;
  }
}

// ---------------------------------------------------------------------------
// K2: per (batch, h-chunk of 64):
//   for j in S = {j : A_mod[j,n] != 0}:
//     h0[j,h] = relu( b0[h] + Yroot[j,h] + sum_{k: A_mod[k,j]!=0} Yrel[k,h] )
//   aggr1[h] += h0[j,h];  h0n[h] = h0[n,h]
// A_mod column bitmasks built in LDS from adj (+ the 3 forced entries).
// ---------------------------------------------------------------------------
__global__ __launch_bounds__(256) void aggr_kernel(
    const float* __restrict__ Y, const int* __restrict__ adj,
    const int* __restrict__ num_nodes, const float* __restrict__ b0,
    float* __restrict__ aggr1, float* __restrict__ h0n)
{
  __shared__ float    Yl[GS][64];      // Yrel chunk [k][h_local]  (32 KB)
  __shared__ uint32_t cm[GS][4];       // column bitmasks of A_mod (2 KB)
  __shared__ float    red[4][64];

  const int hc = blockIdx.x;           // 0..3
  const int b  = blockIdx.y;           // 0..255
  const int n  = num_nodes[b];
  const int tid = threadIdx.x;

  // build column masks: cm[j] bits k where A_mod[k][j] != 0
  if (tid < GS) {
    const int j = tid;
    uint32_t m[4] = {0u, 0u, 0u, 0u};
    const int* ac = adj + (size_t)b * GS * GS + j;
    for (int k = 0; k < GS; ++k) {
      if (ac[(size_t)k * GS] != 0) m[k >> 5] |= (1u << (k & 31));
    }
    if (j == n) {
      m[n >> 5] |= (1u << (n & 31));                       // A[n,n] = 1
      if (n > 0) m[(n - 1) >> 5] |= (1u << ((n - 1) & 31)); // A[n-1,n] = 1
    }
    if (n > 0 && j == n - 1) m[n >> 5] |= (1u << (n & 31)); // A[n,n-1] = 1
    cm[j][0] = m[0]; cm[j][1] = m[1]; cm[j][2] = m[2]; cm[j][3] = m[3];
  }

  // stage Yrel chunk: columns [hc*64, hc*64+64)
  const int hbase = hc * 64;
  for (int idx = tid; idx < GS * 16; idx += 256) {
    const int k  = idx >> 4;
    const int h4 = (idx & 15) * 4;
    *(float4*)&Yl[k][h4] =
        *(const float4*)&Y[(size_t)(b * GS + k) * 512 + hbase + h4];
  }
  __syncthreads();

  const int tg   = tid >> 6;           // wave id: owns j ≡ tg (mod 4)
  const int h    = tid & 63;
  const int habs = hbase + h;

  const uint32_t s0 = cm[n][0], s1 = cm[n][1], s2 = cm[n][2], s3 = cm[n][3];
  const uint32_t S[4] = {s0, s1, s2, s3};

  float aggr = 0.f, hn = 0.f;
  const float bb = b0[habs];

  for (int j = tg; j < GS; j += 4) {
    if (!((S[j >> 5] >> (j & 31)) & 1u)) continue;   // wave-uniform skip
    float acc = bb + Y[(size_t)(b * GS + j) * 512 + 256 + habs];  // root term
#pragma unroll
    for (int w = 0; w < 4; ++w) {
      uint32_t mm = (uint32_t)__builtin_amdgcn_readfirstlane((int)cm[j][w]);
      while (mm) {
        const int k = (w << 5) + __builtin_ctz(mm);
        mm &= mm - 1;
        acc += Yl[k][h];
      }
    }
    acc = fmaxf(acc, 0.f);
    aggr += acc;
    if (j == n) hn = acc;
  }

  if (tg == (n & 3)) h0n[(size_t)b * HSZ + habs] = hn;

  red[tg][h] = aggr;
  __syncthreads();
  if (tg == 0) {
    aggr1[(size_t)b * HSZ + habs] = red[0][h] + red[1][h] + red[2][h] + red[3][h];
  }
}

// ---------------------------------------------------------------------------
// K3: per batch: h1n = relu(aggr1 @ W1_rel + b1 + h0n @ W1_root)
//     logits = h1n @ Wl + bl ; value = h1n @ Wv + bv
// ---------------------------------------------------------------------------
__global__ __launch_bounds__(256) void head_kernel(
    const float* __restrict__ aggr1, const float* __restrict__ h0n,
    const float* __restrict__ W1_rel, const float* __restrict__ b1,
    const float* __restrict__ W1_root,
    const float* __restrict__ Wl, const float* __restrict__ bl,
    const float* __restrict__ Wv, const float* __restrict__ bv,
    float* __restrict__ out)
{
  __shared__ float a1[HSZ];
  __shared__ float rn[HSZ];
  __shared__ float h1[OUTSZ];
  __shared__ float pl[19 * 257];       // +1-style padded reduce buffer

  const int b = blockIdx.x;
  const int t = threadIdx.x;

  a1[t] = aggr1[(size_t)b * HSZ + t];
  rn[t] = h0n[(size_t)b * HSZ + t];
  __syncthreads();

#pragma unroll
  for (int oi = 0; oi < 4; ++oi) {
    const int o = oi * 256 + t;
    float acc = b1[o];
#pragma unroll 8
    for (int hh = 0; hh < HSZ; ++hh) {
      acc = fmaf(a1[hh], W1_rel[(size_t)hh * OUTSZ + o], acc);
      acc = fmaf(rn[hh], W1_root[(size_t)hh * OUTSZ + o], acc);
    }
    h1[o] = fmaxf(acc, 0.f);
  }
  __syncthreads();

  float p[NOUT];
#pragma unroll
  for (int c = 0; c < NOUT; ++c) p[c] = 0.f;
  float pv = 0.f;

#pragma unroll
  for (int oi = 0; oi < 4; ++oi) {
    const int o = oi * 256 + t;
    const float v = h1[o];
    const float* wr = Wl + (size_t)o * NOUT;
#pragma unroll
    for (int c = 0; c < NOUT; ++c) p[c] = fmaf(v, wr[c], p[c]);
    pv = fmaf(v, Wv[o], pv);
  }

#pragma unroll
  for (int c = 0; c < NOUT; ++c) pl[c * 257 + t] = p[c];
  pl[18 * 257 + t] = pv;
  __syncthreads();

  if (t < 19) {
    float sum = 0.f;
    for (int i = 0; i < 256; ++i) sum += pl[t * 257 + i];
    if (t < NOUT) out[(size_t)b * NOUT + t] = sum + bl[t];
    else          out[(size_t)BATCH * NOUT + b] = sum + bv[0];
  }
}

// ---------------------------------------------------------------------------
extern "C" void kernel_launch(void* const* d_in, const int* in_sizes, int n_in,
                              void* d_out, int out_size, void* d_ws, size_t ws_size,
                              hipStream_t stream)
{
  const float* flat      = (const float*)d_in[0];
  const float* nodes     = (const float*)d_in[1];
  const int*   num_nodes = (const int*)  d_in[2];
  const int*   adj       = (const int*)  d_in[3];
  // d_in[4] = seq_lens (unused)
  const float* W0_rel    = (const float*)d_in[5];
  const float* b0        = (const float*)d_in[6];
  const float* W0_root   = (const float*)d_in[7];
  const float* W1_rel    = (const float*)d_in[8];
  const float* b1        = (const float*)d_in[9];
  const float* W1_root   = (const float*)d_in[10];
  const float* Wl        = (const float*)d_in[11];
  const float* bl        = (const float*)d_in[12];
  const float* Wv        = (const float*)d_in[13];
  const float* bv        = (const float*)d_in[14];
  float* out = (float*)d_out;

  float* Y     = (float*)d_ws;                       // 32768 * 512 f32 = 64 MiB
  float* aggr1 = Y + (size_t)32768 * 512;            // 256*256 f32
  float* h0n   = aggr1 + (size_t)BATCH * HSZ;        // 256*256 f32

  gemm0_kernel<<<dim3(512 / 64, 32768 / 64), 256, 0, stream>>>(
      flat, nodes, num_nodes, W0_rel, W0_root, Y);
  aggr_kernel<<<dim3(4, BATCH), 256, 0, stream>>>(
      Y, adj, num_nodes, b0, aggr1, h0n);
  head_kernel<<<BATCH, 256, 0, stream>>>(
      aggr1, h0n, W1_rel, b1, W1_root, Wl, bl, Wv, bv, out);
}

// Round 2
// 492.395 us; speedup vs baseline: 1.6991x; 1.6991x over previous
//
#include <hip/hip_runtime.h>
#include <hip/hip_bf16.h>
#include <cstdint>
#include <cstddef>

#define GS     128
#define OBS    1024
#define HSZ    256
#define OUTSZ  1024
#define NOUT   18
#define BATCH  256

typedef short short8 __attribute__((ext_vector_type(8)));
typedef float f32x4  __attribute__((ext_vector_type(4)));

__device__ __forceinline__ uint32_t f2bf_bits(float f) {
  uint32_t u = __builtin_bit_cast(uint32_t, f);
  return (u + 0x7fffu + ((u >> 16) & 1u)) >> 16;
}
__device__ __forceinline__ float bf_bits2f(uint32_t b) {
  return __builtin_bit_cast(float, b << 16);
}
// 8 floats -> packed bf16 hi (uint4) and residual-lo bf16 (uint4)
__device__ __forceinline__ void cvt8(const float4 a, const float4 b,
                                     uint4& hv, uint4& lv) {
  float v[8] = {a.x, a.y, a.z, a.w, b.x, b.y, b.z, b.w};
  uint32_t h[8], l[8];
#pragma unroll
  for (int e = 0; e < 8; ++e) {
    h[e] = f2bf_bits(v[e]);
    float lo = v[e] - bf_bits2f(h[e]);
    l[e] = f2bf_bits(lo);
  }
  hv = make_uint4(h[0] | (h[1] << 16), h[2] | (h[3] << 16),
                  h[4] | (h[5] << 16), h[6] | (h[7] << 16));
  lv = make_uint4(l[0] | (l[1] << 16), l[2] | (l[3] << 16),
                  l[4] | (l[5] << 16), l[6] | (l[7] << 16));
}

// ---------------------------------------------------------------------------
// P0: transpose W0cat [1024][512] fp32 -> Wt_hi/Wt_lo [512][1024] bf16 bits
// ---------------------------------------------------------------------------
__global__ __launch_bounds__(256) void prep_wt(
    const float* __restrict__ W0_rel, const float* __restrict__ W0_root,
    ushort* __restrict__ Wt_hi, ushort* __restrict__ Wt_lo)
{
  __shared__ float T[64][65];
  const int k0 = blockIdx.x * 64;          // over OBS=1024
  const int n0 = blockIdx.y * 64;          // over 512 cat cols
  const int t = threadIdx.x;
  for (int idx = t; idx < 4096; idx += 256) {
    const int r = idx >> 6, c = idx & 63;
    const int n = n0 + c;
    const float v = (n < HSZ) ? W0_rel[(size_t)(k0 + r) * HSZ + n]
                              : W0_root[(size_t)(k0 + r) * HSZ + (n - HSZ)];
    T[r][c] = v;
  }
  __syncthreads();
  for (int idx = t; idx < 4096; idx += 256) {
    const int r = idx >> 6, c = idx & 63;  // r: n-local, c: k-local
    const float v = T[c][r];
    const uint32_t hb = f2bf_bits(v);
    const float lo = v - bf_bits2f(hb);
    const uint32_t lb = f2bf_bits(lo);
    const size_t off = (size_t)(n0 + r) * OBS + (k0 + c);
    Wt_hi[off] = (ushort)hb;
    Wt_lo[off] = (ushort)lb;
  }
}

// ---------------------------------------------------------------------------
// K1: Y[b*128+g][0:512] = x(b,g) @ [W0_rel | W0_root] via split-bf16 MFMA.
// 128x128 tile, BK=32, 4 waves 2x2, each wave 64x64 (4x4 of 16x16x32 MFMA).
// ---------------------------------------------------------------------------
__global__ __launch_bounds__(256) void gemm0_mfma(
    const float* __restrict__ flat, const float* __restrict__ nodes,
    const int* __restrict__ num_nodes,
    const ushort* __restrict__ Wt_hi, const ushort* __restrict__ Wt_lo,
    float* __restrict__ Y)
{
  __shared__ ushort As_hi[128][40], As_lo[128][40];  // [m][k], stride 40
  __shared__ ushort Bs_hi[128][40], Bs_lo[128][40];  // [n][k]

  const int n0 = blockIdx.x * 128;   // 0..384
  const int b  = blockIdx.y;         // batch = row tile
  const int nb = num_nodes[b];
  const int t  = threadIdx.x;

  // staging assignment: thread -> (row 0..127, 16 k's)
  const int ra = t >> 1;
  const int ca = (t & 1) * 16;
  const float* xsrc = ((ra == nb) ? (flat + (size_t)b * OBS)
                                  : (nodes + ((size_t)b * GS + ra) * OBS)) + ca;
  const ushort* wh = Wt_hi + (size_t)(n0 + ra) * OBS + ca;
  const ushort* wl = Wt_lo + (size_t)(n0 + ra) * OBS + ca;

  const int wv = t >> 6;
  const int wm = wv & 1, wn = wv >> 1;
  const int lane = t & 63;
  const int ln = lane & 15, q = lane >> 4;

  f32x4 acc[4][4] = {};

  for (int kk = 0; kk < OBS; kk += 32) {
    {
      const float4 a0 = *(const float4*)(xsrc + kk);
      const float4 a1 = *(const float4*)(xsrc + kk + 4);
      const float4 a2 = *(const float4*)(xsrc + kk + 8);
      const float4 a3 = *(const float4*)(xsrc + kk + 12);
      uint4 h0, l0, h1, l1;
      cvt8(a0, a1, h0, l0);
      cvt8(a2, a3, h1, l1);
      *(uint4*)&As_hi[ra][ca]     = h0;
      *(uint4*)&As_hi[ra][ca + 8] = h1;
      *(uint4*)&As_lo[ra][ca]     = l0;
      *(uint4*)&As_lo[ra][ca + 8] = l1;
      *(uint4*)&Bs_hi[ra][ca]     = *(const uint4*)(wh + kk);
      *(uint4*)&Bs_hi[ra][ca + 8] = *(const uint4*)(wh + kk + 8);
      *(uint4*)&Bs_lo[ra][ca]     = *(const uint4*)(wl + kk);
      *(uint4*)&Bs_lo[ra][ca + 8] = *(const uint4*)(wl + kk + 8);
    }
    __syncthreads();

    short8 ah[4], al[4], bh[4], bl_[4];
#pragma unroll
    for (int i = 0; i < 4; ++i) {
      ah[i]  = *(const short8*)&As_hi[wm * 64 + i * 16 + ln][q * 8];
      al[i]  = *(const short8*)&As_lo[wm * 64 + i * 16 + ln][q * 8];
      bh[i]  = *(const short8*)&Bs_hi[wn * 64 + i * 16 + ln][q * 8];
      bl_[i] = *(const short8*)&Bs_lo[wn * 64 + i * 16 + ln][q * 8];
    }
#pragma unroll
    for (int i = 0; i < 4; ++i)
#pragma unroll
      for (int j = 0; j < 4; ++j) {
        acc[i][j] = __builtin_amdgcn_mfma_f32_16x16x32_bf16(ah[i], bh[j],  acc[i][j], 0, 0, 0);
        acc[i][j] = __builtin_amdgcn_mfma_f32_16x16x32_bf16(al[i], bh[j],  acc[i][j], 0, 0, 0);
        acc[i][j] = __builtin_amdgcn_mfma_f32_16x16x32_bf16(ah[i], bl_[j], acc[i][j], 0, 0, 0);
      }
    __syncthreads();
  }

  // epilogue: C/D layout col=lane&15, row=(lane>>4)*4+reg   [m89-verified]
#pragma unroll
  for (int i = 0; i < 4; ++i)
#pragma unroll
    for (int j = 0; j < 4; ++j)
#pragma unroll
      for (int r = 0; r < 4; ++r) {
        const int row = wm * 64 + i * 16 + q * 4 + r;
        const int col = n0 + wn * 64 + j * 16 + ln;
        Y[((size_t)b * GS + row) * 512 + col] = acc[i][j][r];
      }
}

// ---------------------------------------------------------------------------
// K2: per (h-half, batch): masked aggregation.
//   cm[j] bits k where A_mod[k][j]!=0 ; S = cm[n]
//   h0[j,h] = relu(b0 + Yroot[j,h] + sum_{k in cm[j]} Yrel[k,h]), j in S
//   Z[b][0:256]=sum_{j in S} h0[j,:],  Z[b][256:512]=h0[n,:]
// ---------------------------------------------------------------------------
__global__ __launch_bounds__(256) void aggr_kernel(
    const float* __restrict__ Y, const int* __restrict__ adj,
    const int* __restrict__ num_nodes, const float* __restrict__ b0,
    float* __restrict__ Z)
{
  __shared__ float    Yl[128][130];     // 66.6 KB
  __shared__ uint32_t rm[128][4];
  __shared__ uint32_t cm[128][4];
  __shared__ float    red[4][128];

  const int hb = blockIdx.x * 128;      // 0 or 128 (h-half)
  const int b  = blockIdx.y;
  const int n  = num_nodes[b];
  const int t  = threadIdx.x;
  const int wv = t >> 6, lane = t & 63;

  // row masks via ballot (coalesced adj reads)
  for (int i = 0; i < 32; ++i) {
    const int k = wv * 32 + i;
    const int* arow = adj + ((size_t)b * GS + k) * GS;
    const unsigned long long m0 = __ballot(arow[lane] != 0);
    const unsigned long long m1 = __ballot(arow[64 + lane] != 0);
    if (lane == 0) {
      rm[k][0] = (uint32_t)m0; rm[k][1] = (uint32_t)(m0 >> 32);
      rm[k][2] = (uint32_t)m1; rm[k][3] = (uint32_t)(m1 >> 32);
    }
  }
  // stage Yrel chunk
  for (int idx = t; idx < 128 * 32; idx += 256) {
    const int k = idx >> 5, c4 = (idx & 31) * 4;
    *(float4*)&Yl[k][c4] =
        *(const float4*)&Y[((size_t)b * GS + k) * 512 + hb + c4];
  }
  __syncthreads();

  // bit transpose rm -> cm
  if (t < 128) {
    uint32_t c0 = 0, c1 = 0, c2 = 0, c3 = 0;
    const int w = t >> 5, sh = t & 31;
    for (int k = 0; k < 128; ++k) {
      const uint32_t bit = (rm[k][w] >> sh) & 1u;
      if (k < 32)      c0 |= bit << k;
      else if (k < 64) c1 |= bit << (k - 32);
      else if (k < 96) c2 |= bit << (k - 64);
      else             c3 |= bit << (k - 96);
    }
    cm[t][0] = c0; cm[t][1] = c1; cm[t][2] = c2; cm[t][3] = c3;
  }
  __syncthreads();
  if (t == 0) {
    cm[n][n >> 5] |= 1u << (n & 31);                    // A[n,n]
    if (n > 0) {
      cm[n - 1][n >> 5] |= 1u << (n & 31);              // A[n,n-1]
      cm[n][(n - 1) >> 5] |= 1u << ((n - 1) & 31);      // A[n-1,n]
    }
  }
  __syncthreads();

  const uint32_t S[4] = {cm[n][0], cm[n][1], cm[n][2], cm[n][3]};
  const int h2 = lane * 2;
  const float bb0 = b0[hb + h2], bb1 = b0[hb + h2 + 1];

  float a0 = 0.f, a1 = 0.f, hn0 = 0.f, hn1 = 0.f;

  for (int w = 0; w < 4; ++w) {
    uint32_t mm = S[w];
    while (mm) {
      const int j = w * 32 + __builtin_ctz(mm);
      mm &= mm - 1;
      if ((j & 3) != wv) continue;
      const float2 rt =
          *(const float2*)&Y[((size_t)b * GS + j) * 512 + 256 + hb + h2];
      float s0 = bb0 + rt.x, s1 = bb1 + rt.y;
#pragma unroll
      for (int w2 = 0; w2 < 4; ++w2) {
        uint32_t m2 = cm[j][w2];
        while (m2) {
          const int k = w2 * 32 + __builtin_ctz(m2);
          m2 &= m2 - 1;
          const float2 yv = *(const float2*)&Yl[k][h2];
          s0 += yv.x; s1 += yv.y;
        }
      }
      s0 = fmaxf(s0, 0.f); s1 = fmaxf(s1, 0.f);
      a0 += s0; a1 += s1;
      if (j == n) { hn0 = s0; hn1 = s1; }
    }
  }

  if (wv == (n & 3)) {
    Z[(size_t)b * 512 + 256 + hb + h2]     = hn0;
    Z[(size_t)b * 512 + 256 + hb + h2 + 1] = hn1;
  }
  red[wv][h2] = a0; red[wv][h2 + 1] = a1;
  __syncthreads();
  if (t < 128)
    Z[(size_t)b * 512 + hb + t] = red[0][t] + red[1][t] + red[2][t] + red[3][t];
}

// ---------------------------------------------------------------------------
// K3: h1[256][1024] = relu(Z @ [W1_rel ; W1_root] + b1)   (fp32 tiled GEMM)
// ---------------------------------------------------------------------------
__global__ __launch_bounds__(256) void gemm1_kernel(
    const float* __restrict__ Z, const float* __restrict__ W1_rel,
    const float* __restrict__ W1_root, const float* __restrict__ b1,
    float* __restrict__ h1)
{
  __shared__ float As[16][64];
  __shared__ float Bs[16][64];

  const int n0 = blockIdx.x * 64;   // over 1024
  const int m0 = blockIdx.y * 64;   // over 256
  const int t = threadIdx.x;
  const int tx = t & 15, ty = t >> 4;
  const int arow = t >> 2, acol4 = (t & 3) * 4;
  const int brow = t >> 4, bcol4 = (t & 15) * 4;

  float acc[4][4] = {};

  for (int kk = 0; kk < 512; kk += 16) {
    const float4 av = *(const float4*)&Z[(size_t)(m0 + arow) * 512 + kk + acol4];
    const int k = kk + brow;
    const float* Bp = (k < HSZ) ? (W1_rel + (size_t)k * OUTSZ)
                                : (W1_root + (size_t)(k - HSZ) * OUTSZ);
    const float4 bv = *(const float4*)(Bp + n0 + bcol4);
    As[acol4 + 0][arow] = av.x;
    As[acol4 + 1][arow] = av.y;
    As[acol4 + 2][arow] = av.z;
    As[acol4 + 3][arow] = av.w;
    *(float4*)&Bs[brow][bcol4] = bv;
    __syncthreads();
#pragma unroll
    for (int k2 = 0; k2 < 16; ++k2) {
      const float4 a = *(const float4*)&As[k2][ty * 4];
      const float4 qv = *(const float4*)&Bs[k2][tx * 4];
      const float af[4] = {a.x, a.y, a.z, a.w};
      const float qf[4] = {qv.x, qv.y, qv.z, qv.w};
#pragma unroll
      for (int i = 0; i < 4; ++i)
#pragma unroll
        for (int j = 0; j < 4; ++j)
          acc[i][j] = fmaf(af[i], qf[j], acc[i][j]);
    }
    __syncthreads();
  }

#pragma unroll
  for (int i = 0; i < 4; ++i) {
    const int row = m0 + ty * 4 + i;
    const int colb = n0 + tx * 4;
    float4 st;
    st.x = fmaxf(acc[i][0] + b1[colb + 0], 0.f);
    st.y = fmaxf(acc[i][1] + b1[colb + 1], 0.f);
    st.z = fmaxf(acc[i][2] + b1[colb + 2], 0.f);
    st.w = fmaxf(acc[i][3] + b1[colb + 3], 0.f);
    *(float4*)&h1[(size_t)row * OUTSZ + colb] = st;
  }
}

// ---------------------------------------------------------------------------
// K4: logits/value head from h1 rows.
// ---------------------------------------------------------------------------
__global__ __launch_bounds__(256) void head2_kernel(
    const float* __restrict__ h1, const float* __restrict__ Wl,
    const float* __restrict__ bl, const float* __restrict__ Wv,
    const float* __restrict__ bv, float* __restrict__ out)
{
  __shared__ float pl[19 * 257];
  const int b = blockIdx.x;
  const int t = threadIdx.x;

  float p[NOUT];
#pragma unroll
  for (int c = 0; c < NOUT; ++c) p[c] = 0.f;
  float pv = 0.f;

#pragma unroll
  for (int oi = 0; oi < 4; ++oi) {
    const int k = oi * 256 + t;
    const float v = h1[(size_t)b * OUTSZ + k];
    const float* wr = Wl + (size_t)k * NOUT;
#pragma unroll
    for (int c = 0; c < NOUT; ++c) p[c] = fmaf(v, wr[c], p[c]);
    pv = fmaf(v, Wv[k], pv);
  }

#pragma unroll
  for (int c = 0; c < NOUT; ++c) pl[c * 257 + t] = p[c];
  pl[18 * 257 + t] = pv;
  __syncthreads();

  if (t < 19) {
    float sum = 0.f;
    for (int i = 0; i < 256; ++i) sum += pl[t * 257 + i];
    if (t < NOUT) out[(size_t)b * NOUT + t] = sum + bl[t];
    else          out[(size_t)BATCH * NOUT + b] = sum + bv[0];
  }
}

// ---------------------------------------------------------------------------
extern "C" void kernel_launch(void* const* d_in, const int* in_sizes, int n_in,
                              void* d_out, int out_size, void* d_ws, size_t ws_size,
                              hipStream_t stream)
{
  const float* flat      = (const float*)d_in[0];
  const float* nodes     = (const float*)d_in[1];
  const int*   num_nodes = (const int*)  d_in[2];
  const int*   adj       = (const int*)  d_in[3];
  const float* W0_rel    = (const float*)d_in[5];
  const float* b0        = (const float*)d_in[6];
  const float* W0_root   = (const float*)d_in[7];
  const float* W1_rel    = (const float*)d_in[8];
  const float* b1        = (const float*)d_in[9];
  const float* W1_root   = (const float*)d_in[10];
  const float* Wl        = (const float*)d_in[11];
  const float* bl        = (const float*)d_in[12];
  const float* Wv        = (const float*)d_in[13];
  const float* bv        = (const float*)d_in[14];
  float* out = (float*)d_out;

  float*  Y     = (float*)d_ws;                        // 32768*512 f32 = 64 MiB
  float*  Z     = Y + (size_t)32768 * 512;             // 256*512 f32
  float*  h1    = Z + (size_t)BATCH * 512;             // 256*1024 f32
  ushort* Wt_hi = (ushort*)(h1 + (size_t)BATCH * OUTSZ);   // 512*1024 bf16
  ushort* Wt_lo = Wt_hi + (size_t)512 * OBS;               // 512*1024 bf16

  prep_wt<<<dim3(16, 8), 256, 0, stream>>>(W0_rel, W0_root, Wt_hi, Wt_lo);
  gemm0_mfma<<<dim3(4, BATCH), 256, 0, stream>>>(
      flat, nodes, num_nodes, Wt_hi, Wt_lo, Y);
  aggr_kernel<<<dim3(2, BATCH), 256, 0, stream>>>(Y, adj, num_nodes, b0, Z);
  gemm1_kernel<<<dim3(16, 4), 256, 0, stream>>>(Z, W1_rel, W1_root, b1, h1);
  head2_kernel<<<BATCH, 256, 0, stream>>>(h1, Wl, bl, Wv, bv, out);
}

// Round 3
// 491.145 us; speedup vs baseline: 1.7035x; 1.0025x over previous
//
#include <hip/hip_runtime.h>
#include <hip/hip_bf16.h>
#include <cstdint>
#include <cstddef>

#define GS     128
#define OBS    1024
#define HSZ    256
#define OUTSZ  1024
#define NOUT   18
#define BATCH  256

typedef short  short8  __attribute__((ext_vector_type(8)));
typedef float  f32x4   __attribute__((ext_vector_type(4)));
typedef unsigned short ushort8 __attribute__((ext_vector_type(8)));

__device__ __forceinline__ uint32_t f2bf_bits(float f) {
  uint32_t u = __builtin_bit_cast(uint32_t, f);
  return (u + 0x7fffu + ((u >> 16) & 1u)) >> 16;
}
__device__ __forceinline__ float bf_bits2f(uint32_t b) {
  return __builtin_bit_cast(float, b << 16);
}
// 8 floats -> packed bf16 (uint4), RNE
__device__ __forceinline__ uint4 cvt8s(const float4 a, const float4 b) {
  float v[8] = {a.x, a.y, a.z, a.w, b.x, b.y, b.z, b.w};
  uint32_t h[8];
#pragma unroll
  for (int e = 0; e < 8; ++e) h[e] = f2bf_bits(v[e]);
  return make_uint4(h[0] | (h[1] << 16), h[2] | (h[3] << 16),
                    h[4] | (h[5] << 16), h[6] | (h[7] << 16));
}

// ---------------------------------------------------------------------------
// P0: W0cat [1024][512] fp32 -> Wt [512][1024] bf16 (transposed, k-contiguous)
// ---------------------------------------------------------------------------
__global__ __launch_bounds__(256) void prep_wt(
    const float* __restrict__ W0_rel, const float* __restrict__ W0_root,
    ushort* __restrict__ Wt)
{
  __shared__ float T[64][65];
  const int k0 = blockIdx.x * 64;          // over OBS
  const int n0 = blockIdx.y * 64;          // over 512 cat cols
  const int t = threadIdx.x;
  for (int idx = t; idx < 4096; idx += 256) {
    const int r = idx >> 6, c = idx & 63;
    const int n = n0 + c;
    T[r][c] = (n < HSZ) ? W0_rel[(size_t)(k0 + r) * HSZ + n]
                        : W0_root[(size_t)(k0 + r) * HSZ + (n - HSZ)];
  }
  __syncthreads();
  for (int idx = t; idx < 4096; idx += 256) {
    const int r = idx >> 6, c = idx & 63;  // r: n-local, c: k-local
    Wt[(size_t)(n0 + r) * OBS + (k0 + c)] = (ushort)f2bf_bits(T[c][r]);
  }
}

// ---------------------------------------------------------------------------
// P1: per-batch adjacency column masks cm[j] (bit k set iff A_mod[k][j]!=0),
//     with the forced diagonal/chain entries. Stored to global cm_g[b][j][4].
// ---------------------------------------------------------------------------
__global__ __launch_bounds__(256) void masks_kernel(
    const int* __restrict__ adj, const int* __restrict__ num_nodes,
    uint32_t* __restrict__ cm_g)
{
  __shared__ uint32_t rm[128][4];
  __shared__ uint32_t cm[128][4];
  const int b = blockIdx.x;
  const int n = num_nodes[b];
  const int t = threadIdx.x;
  const int wv = t >> 6, lane = t & 63;

#pragma unroll 4
  for (int i = 0; i < 32; ++i) {
    const int k = wv * 32 + i;
    const int* arow = adj + ((size_t)b * GS + k) * GS;
    const unsigned long long m0 = __ballot(arow[lane] != 0);
    const unsigned long long m1 = __ballot(arow[64 + lane] != 0);
    if (lane == 0) {
      rm[k][0] = (uint32_t)m0; rm[k][1] = (uint32_t)(m0 >> 32);
      rm[k][2] = (uint32_t)m1; rm[k][3] = (uint32_t)(m1 >> 32);
    }
  }
  __syncthreads();
  if (t < 128) {
    uint32_t c0 = 0, c1 = 0, c2 = 0, c3 = 0;
    const int w = t >> 5, sh = t & 31;
#pragma unroll 8
    for (int k = 0; k < 128; ++k) {
      const uint32_t bit = (rm[k][w] >> sh) & 1u;
      if (k < 32)      c0 |= bit << k;
      else if (k < 64) c1 |= bit << (k - 32);
      else if (k < 96) c2 |= bit << (k - 64);
      else             c3 |= bit << (k - 96);
    }
    cm[t][0] = c0; cm[t][1] = c1; cm[t][2] = c2; cm[t][3] = c3;
  }
  __syncthreads();
  if (t == 0) {
    cm[n][n >> 5] |= 1u << (n & 31);                    // A[n,n]
    if (n > 0) {
      cm[n - 1][n >> 5] |= 1u << (n & 31);              // A[n,n-1]
      cm[n][(n - 1) >> 5] |= 1u << ((n - 1) & 31);      // A[n-1,n]
    }
  }
  __syncthreads();
  for (int idx = t; idx < 512; idx += 256)
    cm_g[(size_t)b * 512 + idx] = ((const uint32_t*)cm)[idx];
}

// ---------------------------------------------------------------------------
// K1: Ybf[b*128+g][0:512] = bf16( x(b,g) @ [W0_rel | W0_root] )  (single bf16)
// 128x128 tile, BK=32, 4 waves 2x2, 16 MFMA 16x16x32 per K-step per wave.
// ---------------------------------------------------------------------------
__global__ __launch_bounds__(256) void gemm0_mfma(
    const float* __restrict__ flat, const float* __restrict__ nodes,
    const int* __restrict__ num_nodes, const ushort* __restrict__ Wt,
    ushort* __restrict__ Ybf)
{
  __shared__ ushort As[128][40];   // [m][k], stride 40 (80 B, 16B-aligned rows)
  __shared__ ushort Bs[128][40];   // [n][k]

  const int n0 = blockIdx.x * 128;
  const int b  = blockIdx.y;
  const int nb = num_nodes[b];
  const int t  = threadIdx.x;

  const int ra = t >> 1;
  const int ca = (t & 1) * 16;
  const float* xsrc = ((ra == nb) ? (flat + (size_t)b * OBS)
                                  : (nodes + ((size_t)b * GS + ra) * OBS)) + ca;
  const ushort* wsrc = Wt + (size_t)(n0 + ra) * OBS + ca;

  const int wv = t >> 6;
  const int wm = wv & 1, wn = wv >> 1;
  const int lane = t & 63;
  const int ln = lane & 15, q = lane >> 4;

  f32x4 acc[4][4] = {};

  for (int kk = 0; kk < OBS; kk += 32) {
    {
      const float4 a0 = *(const float4*)(xsrc + kk);
      const float4 a1 = *(const float4*)(xsrc + kk + 4);
      const float4 a2 = *(const float4*)(xsrc + kk + 8);
      const float4 a3 = *(const float4*)(xsrc + kk + 12);
      *(uint4*)&As[ra][ca]     = cvt8s(a0, a1);
      *(uint4*)&As[ra][ca + 8] = cvt8s(a2, a3);
      *(uint4*)&Bs[ra][ca]     = *(const uint4*)(wsrc + kk);
      *(uint4*)&Bs[ra][ca + 8] = *(const uint4*)(wsrc + kk + 8);
    }
    __syncthreads();

    short8 ah[4], bh[4];
#pragma unroll
    for (int i = 0; i < 4; ++i) {
      ah[i] = *(const short8*)&As[wm * 64 + i * 16 + ln][q * 8];
      bh[i] = *(const short8*)&Bs[wn * 64 + i * 16 + ln][q * 8];
    }
#pragma unroll
    for (int i = 0; i < 4; ++i)
#pragma unroll
      for (int j = 0; j < 4; ++j)
        acc[i][j] = __builtin_amdgcn_mfma_f32_16x16x32_bf16(ah[i], bh[j], acc[i][j], 0, 0, 0);
    __syncthreads();
  }

  // C/D layout: col = lane&15, row = (lane>>4)*4 + reg   [m89-verified]
#pragma unroll
  for (int i = 0; i < 4; ++i)
#pragma unroll
    for (int j = 0; j < 4; ++j)
#pragma unroll
      for (int r = 0; r < 4; ++r) {
        const int row = wm * 64 + i * 16 + q * 4 + r;
        const int col = n0 + wn * 64 + j * 16 + ln;
        Ybf[((size_t)b * GS + row) * 512 + col] = (ushort)f2bf_bits(acc[i][j][r]);
      }
}

// ---------------------------------------------------------------------------
// K2: per (h-quarter, batch):
//   for j in S=cm[n]: h0[j,h]=relu(b0+Yroot[j,h]+sum_{k in cm[j]} Yrel[k,h])
//   Z[b][h]      = sum_{j in S} h0[j,h]     (h in [0,256))
//   Z[b][256+h]  = h0[n,h]
// ---------------------------------------------------------------------------
__global__ __launch_bounds__(256) void aggr_kernel(
    const ushort* __restrict__ Ybf, const uint32_t* __restrict__ cm_g,
    const int* __restrict__ num_nodes, const float* __restrict__ b0,
    float* __restrict__ Z)
{
  __shared__ float    Yl[128][64];    // 32 KB
  __shared__ uint32_t cmL[128][4];    // 2 KB
  __shared__ int      jl[128];
  __shared__ int      jcnt;
  __shared__ float    red[4][64];

  const int hq = blockIdx.x;          // 0..3
  const int b  = blockIdx.y;
  const int hb = hq * 64;
  const int n  = num_nodes[b];
  const int t  = threadIdx.x;
  const int wv = t >> 6, lane = t & 63;

  if (t == 0) jcnt = 0;
  for (int idx = t; idx < 512; idx += 256)
    ((uint32_t*)cmL)[idx] = cm_g[(size_t)b * 512 + idx];

  // stage Yrel quarter (bf16 -> fp32): rows k, cols hb..hb+63
  {
    const int chunk = t & 7;          // 8 x 16B chunks per row
    for (int it = 0; it < 4; ++it) {
      const int k = (t >> 3) + it * 32;
      const ushort8 v =
          *(const ushort8*)&Ybf[((size_t)b * GS + k) * 512 + hb + chunk * 8];
      float4 f0, f1;
      f0.x = bf_bits2f(v[0]); f0.y = bf_bits2f(v[1]);
      f0.z = bf_bits2f(v[2]); f0.w = bf_bits2f(v[3]);
      f1.x = bf_bits2f(v[4]); f1.y = bf_bits2f(v[5]);
      f1.z = bf_bits2f(v[6]); f1.w = bf_bits2f(v[7]);
      *(float4*)&Yl[k][chunk * 8]     = f0;
      *(float4*)&Yl[k][chunk * 8 + 4] = f1;
    }
  }
  __syncthreads();

  // build j-list from S = cm[n]
  if (t < 128) {
    if ((cmL[n][t >> 5] >> (t & 31)) & 1u) {
      const int p = atomicAdd(&jcnt, 1);
      jl[p] = t;
    }
  }
  __syncthreads();

  const int cnt = jcnt;
  const float bb = b0[hb + lane];
  float asum = 0.f;

  for (int idx = wv; idx < cnt; idx += 4) {
    const int j = jl[idx];
    float acc = bb +
        bf_bits2f(Ybf[((size_t)b * GS + j) * 512 + 256 + hb + lane]);
#pragma unroll
    for (int w = 0; w < 4; ++w) {
      uint32_t mm = cmL[j][w];
      while (mm) {
        const int k = (w << 5) + __builtin_ctz(mm);
        mm &= mm - 1;
        acc += Yl[k][lane];
      }
    }
    acc = fmaxf(acc, 0.f);
    asum += acc;
    if (j == n) Z[(size_t)b * 512 + 256 + hb + lane] = acc;
  }

  red[wv][lane] = asum;
  __syncthreads();
  if (t < 64)
    Z[(size_t)b * 512 + hb + t] = red[0][t] + red[1][t] + red[2][t] + red[3][t];
}

// ---------------------------------------------------------------------------
// K3 (fused): per batch b:
//   h1 = relu(Z[b] @ [W1_rel ; W1_root] + b1)  (fp32, h1 stays in LDS)
//   logits = h1 @ Wl + bl ; value = h1 @ Wv + bv
// ---------------------------------------------------------------------------
__global__ __launch_bounds__(256) void gemm1_head(
    const float* __restrict__ Z, const float* __restrict__ W1_rel,
    const float* __restrict__ W1_root, const float* __restrict__ b1,
    const float* __restrict__ Wl, const float* __restrict__ bl,
    const float* __restrict__ Wv, const float* __restrict__ bv,
    float* __restrict__ out)
{
  __shared__ float Zl[512];
  __shared__ float h1[OUTSZ];
  __shared__ float WlL[OUTSZ * NOUT];   // 72 KB
  __shared__ float WvL[OUTSZ];          // 4 KB
  __shared__ float pl[19 * 257];        // 19.5 KB

  const int b = blockIdx.x;
  const int t = threadIdx.x;

  Zl[t]       = Z[(size_t)b * 512 + t];
  Zl[256 + t] = Z[(size_t)b * 512 + 256 + t];
  for (int idx = t; idx < OUTSZ * NOUT / 4; idx += 256)
    *(float4*)&WlL[idx * 4] = *(const float4*)&Wl[idx * 4];
  *(float4*)&WvL[t * 4] = *(const float4*)&Wv[t * 4];
  __syncthreads();

  // gemm1: thread t owns cols [t*4, t*4+4)
  {
    const int o4 = t * 4;
    float4 acc = *(const float4*)&b1[o4];
#pragma unroll 4
    for (int h = 0; h < HSZ; ++h) {
      const float a = Zl[h];
      const float4 w = *(const float4*)&W1_rel[(size_t)h * OUTSZ + o4];
      acc.x = fmaf(a, w.x, acc.x); acc.y = fmaf(a, w.y, acc.y);
      acc.z = fmaf(a, w.z, acc.z); acc.w = fmaf(a, w.w, acc.w);
    }
#pragma unroll 4
    for (int h = 0; h < HSZ; ++h) {
      const float a = Zl[256 + h];
      const float4 w = *(const float4*)&W1_root[(size_t)h * OUTSZ + o4];
      acc.x = fmaf(a, w.x, acc.x); acc.y = fmaf(a, w.y, acc.y);
      acc.z = fmaf(a, w.z, acc.z); acc.w = fmaf(a, w.w, acc.w);
    }
    acc.x = fmaxf(acc.x, 0.f); acc.y = fmaxf(acc.y, 0.f);
    acc.z = fmaxf(acc.z, 0.f); acc.w = fmaxf(acc.w, 0.f);
    *(float4*)&h1[o4] = acc;
  }
  __syncthreads();

  // head
  float p[NOUT];
#pragma unroll
  for (int c = 0; c < NOUT; ++c) p[c] = 0.f;
  float pv = 0.f;
#pragma unroll
  for (int oi = 0; oi < 4; ++oi) {
    const int o = oi * 256 + t;
    const float v = h1[o];
    const float* wr = &WlL[o * NOUT];
#pragma unroll
    for (int c = 0; c < NOUT; ++c) p[c] = fmaf(v, wr[c], p[c]);
    pv = fmaf(v, WvL[o], pv);
  }
#pragma unroll
  for (int c = 0; c < NOUT; ++c) pl[c * 257 + t] = p[c];
  pl[18 * 257 + t] = pv;
  __syncthreads();

  if (t < 19) {
    float sum = 0.f;
    for (int i = 0; i < 256; ++i) sum += pl[t * 257 + i];
    if (t < NOUT) out[(size_t)b * NOUT + t] = sum + bl[t];
    else          out[(size_t)BATCH * NOUT + b] = sum + bv[0];
  }
}

// ---------------------------------------------------------------------------
extern "C" void kernel_launch(void* const* d_in, const int* in_sizes, int n_in,
                              void* d_out, int out_size, void* d_ws, size_t ws_size,
                              hipStream_t stream)
{
  const float* flat      = (const float*)d_in[0];
  const float* nodes     = (const float*)d_in[1];
  const int*   num_nodes = (const int*)  d_in[2];
  const int*   adj       = (const int*)  d_in[3];
  const float* W0_rel    = (const float*)d_in[5];
  const float* b0        = (const float*)d_in[6];
  const float* W0_root   = (const float*)d_in[7];
  const float* W1_rel    = (const float*)d_in[8];
  const float* b1        = (const float*)d_in[9];
  const float* W1_root   = (const float*)d_in[10];
  const float* Wl        = (const float*)d_in[11];
  const float* bl        = (const float*)d_in[12];
  const float* Wv        = (const float*)d_in[13];
  const float* bv        = (const float*)d_in[14];
  float* out = (float*)d_out;

  char* ws = (char*)d_ws;
  ushort*   Ybf  = (ushort*)ws;                       ws += (size_t)32768 * 512 * 2;  // 32 MiB
  ushort*   Wt   = (ushort*)ws;                       ws += (size_t)512 * OBS * 2;    // 1 MiB
  uint32_t* cm_g = (uint32_t*)ws;                     ws += (size_t)BATCH * 512 * 4;  // 512 KiB
  float*    Z    = (float*)ws;                        ws += (size_t)BATCH * 512 * 4;  // 512 KiB

  prep_wt<<<dim3(16, 8), 256, 0, stream>>>(W0_rel, W0_root, Wt);
  masks_kernel<<<BATCH, 256, 0, stream>>>(adj, num_nodes, cm_g);
  gemm0_mfma<<<dim3(4, BATCH), 256, 0, stream>>>(
      flat, nodes, num_nodes, Wt, Ybf);
  aggr_kernel<<<dim3(4, BATCH), 256, 0, stream>>>(Ybf, cm_g, num_nodes, b0, Z);
  gemm1_head<<<BATCH, 256, 0, stream>>>(
      Z, W1_rel, W1_root, b1, Wl, bl, Wv, bv, out);
}

// Round 4
// 373.701 us; speedup vs baseline: 2.2388x; 1.3143x over previous
//
#include <hip/hip_runtime.h>
#include <hip/hip_bf16.h>
#include <cstdint>
#include <cstddef>

#define GS     128
#define OBS    1024
#define HSZ    256
#define OUTSZ  1024
#define NOUT   18
#define BATCH  256

typedef short  short8  __attribute__((ext_vector_type(8)));
typedef float  f32x4   __attribute__((ext_vector_type(4)));

__device__ __forceinline__ uint32_t f2bf_bits(float f) {
  uint32_t u = __builtin_bit_cast(uint32_t, f);
  return (u + 0x7fffu + ((u >> 16) & 1u)) >> 16;
}
__device__ __forceinline__ float bf_bits2f(uint32_t b) {
  return __builtin_bit_cast(float, b << 16);
}
__device__ __forceinline__ uint4 cvt8s(const float4 a, const float4 b) {
  float v[8] = {a.x, a.y, a.z, a.w, b.x, b.y, b.z, b.w};
  uint32_t h[8];
#pragma unroll
  for (int e = 0; e < 8; ++e) h[e] = f2bf_bits(v[e]);
  return make_uint4(h[0] | (h[1] << 16), h[2] | (h[3] << 16),
                    h[4] | (h[5] << 16), h[6] | (h[7] << 16));
}

// ---------------------------------------------------------------------------
// P0: W0cat [1024][512] fp32 -> Wt [512][1024] bf16 (transposed, k-contiguous)
// ---------------------------------------------------------------------------
__global__ __launch_bounds__(256) void prep_wt(
    const float* __restrict__ W0_rel, const float* __restrict__ W0_root,
    ushort* __restrict__ Wt)
{
  __shared__ float T[64][65];
  const int k0 = blockIdx.x * 64;
  const int n0 = blockIdx.y * 64;
  const int t = threadIdx.x;
  for (int idx = t; idx < 4096; idx += 256) {
    const int r = idx >> 6, c = idx & 63;
    const int n = n0 + c;
    T[r][c] = (n < HSZ) ? W0_rel[(size_t)(k0 + r) * HSZ + n]
                        : W0_root[(size_t)(k0 + r) * HSZ + (n - HSZ)];
  }
  __syncthreads();
  for (int idx = t; idx < 4096; idx += 256) {
    const int r = idx >> 6, c = idx & 63;
    Wt[(size_t)(n0 + r) * OBS + (k0 + c)] = (ushort)f2bf_bits(T[c][r]);
  }
}

// ---------------------------------------------------------------------------
// P1: WlT[19][1024]: rows 0..17 = Wl^T, row 18 = Wv
// ---------------------------------------------------------------------------
__global__ __launch_bounds__(256) void prep_wlt(
    const float* __restrict__ Wl, const float* __restrict__ Wv,
    float* __restrict__ WlT)
{
  const int t = threadIdx.x;
  for (int o = t; o < OUTSZ; o += 256) {
#pragma unroll
    for (int c = 0; c < NOUT; ++c) WlT[(size_t)c * OUTSZ + o] = Wl[(size_t)o * NOUT + c];
    WlT[(size_t)18 * OUTSZ + o] = Wv[o];
  }
}

// ---------------------------------------------------------------------------
// K1: YT[b][h][k] bf16, h in [0,256), k in [0,256):
//   k<128 : YT[b][h][k]   = Yrel[k][h]  = (x @ W0_rel)^T
//   k>=128: YT[b][h][128+j] = Yroot[j][h] = (x @ W0_root)^T
// Transposed output comes free by swapping MFMA operands (both frags [row][k]).
// 128x128 tile, BK=32, prefetch-pipelined.
// ---------------------------------------------------------------------------
__global__ __launch_bounds__(256) void gemm0_mfma(
    const float* __restrict__ flat, const float* __restrict__ nodes,
    const int* __restrict__ num_nodes, const ushort* __restrict__ Wt,
    ushort* __restrict__ YT)
{
  __shared__ ushort As[128][40];   // [node-row][k]
  __shared__ ushort Bs[128][40];   // [n-col][k]

  const int x  = blockIdx.x;       // 0..3 column tile
  const int b  = blockIdx.y;
  const int n0 = x * 128;
  const int nb = num_nodes[b];
  const int t  = threadIdx.x;

  const int ra = t >> 1;
  const int ca = (t & 1) * 16;
  const float* xsrc = ((ra == nb) ? (flat + (size_t)b * OBS)
                                  : (nodes + ((size_t)b * GS + ra) * OBS)) + ca;
  const ushort* wsrc = Wt + (size_t)(n0 + ra) * OBS + ca;

  const int wv = t >> 6;
  const int wm = wv & 1, wn = wv >> 1;
  const int lane = t & 63;
  const int ln = lane & 15, q = lane >> 4;

  f32x4 acc[4][4] = {};   // acc[jj][ii]: D rows = Wt-cols (h), cols = node rows

  float4 a0 = *(const float4*)(xsrc);
  float4 a1 = *(const float4*)(xsrc + 4);
  float4 a2 = *(const float4*)(xsrc + 8);
  float4 a3 = *(const float4*)(xsrc + 12);
  uint4 wb0 = *(const uint4*)(wsrc);
  uint4 wb1 = *(const uint4*)(wsrc + 8);

  for (int ks = 0; ks < 32; ++ks) {
    *(uint4*)&As[ra][ca]     = cvt8s(a0, a1);
    *(uint4*)&As[ra][ca + 8] = cvt8s(a2, a3);
    *(uint4*)&Bs[ra][ca]     = wb0;
    *(uint4*)&Bs[ra][ca + 8] = wb1;
    __syncthreads();

    if (ks < 31) {           // prefetch next K-slice during MFMA phase
      const int kk = (ks + 1) * 32;
      a0 = *(const float4*)(xsrc + kk);
      a1 = *(const float4*)(xsrc + kk + 4);
      a2 = *(const float4*)(xsrc + kk + 8);
      a3 = *(const float4*)(xsrc + kk + 12);
      wb0 = *(const uint4*)(wsrc + kk);
      wb1 = *(const uint4*)(wsrc + kk + 8);
    }

    short8 ah[4], bh[4];
#pragma unroll
    for (int i = 0; i < 4; ++i) {
      ah[i] = *(const short8*)&As[wm * 64 + i * 16 + ln][q * 8];
      bh[i] = *(const short8*)&Bs[wn * 64 + i * 16 + ln][q * 8];
    }
#pragma unroll
    for (int jj = 0; jj < 4; ++jj)
#pragma unroll
      for (int ii = 0; ii < 4; ++ii)
        acc[jj][ii] = __builtin_amdgcn_mfma_f32_16x16x32_bf16(
            bh[jj], ah[ii], acc[jj][ii], 0, 0, 0);  // swapped => transposed D
    __syncthreads();
  }

  // D row m = h-local (q*4+r within 16), D col = node index (ln within 16)
  const int h0 = (x & 1) * 128;
  const int k0 = (x >> 1) * 128;
#pragma unroll
  for (int jj = 0; jj < 4; ++jj)
#pragma unroll
    for (int ii = 0; ii < 4; ++ii)
#pragma unroll
      for (int r = 0; r < 4; ++r) {
        const int h = h0 + wn * 64 + jj * 16 + q * 4 + r;
        const int k = k0 + wm * 64 + ii * 16 + ln;
        YT[((size_t)b * 256 + h) * 256 + k] = (ushort)f2bf_bits(acc[jj][ii][r]);
      }
}

// ---------------------------------------------------------------------------
// K2 (fused, one block per batch):
//   A: adjacency ballots -> row masks -> column masks cm[j] (+forced entries)
//   B: P[j][h] = sum_k [A^T | I][j][k] * YT[h][k]  via MFMA (A-frag from bits)
//   C: v=relu(b0+P); aggr1[h]=sum_{j in S} v; h0n[h]=v at j==n
//   D: h1 = relu(aggr1@W1_rel + h0n@W1_root + b1)      (fp32)
//   E: logits/value via WlT + shuffle reduce
// ---------------------------------------------------------------------------
__global__ __launch_bounds__(256) void fused_tail(
    const ushort* __restrict__ YT, const int* __restrict__ adj,
    const int* __restrict__ num_nodes, const float* __restrict__ b0,
    const float* __restrict__ W1_rel, const float* __restrict__ W1_root,
    const float* __restrict__ b1, const float* __restrict__ WlT,
    const float* __restrict__ bl, const float* __restrict__ bv,
    float* __restrict__ out)
{
  __shared__ ushort   Ys[256][264];     // 132 KB, pad: lane-stride 132 words
  __shared__ uint32_t rm[128][4];
  __shared__ uint32_t cmL[128][4];
  __shared__ float    a1_s[256];
  __shared__ float    h0n_s[256];
  __shared__ float    h1[OUTSZ];
  __shared__ float    redq[4][4][64];
  __shared__ float    pl[20][4];

  const int b = blockIdx.x;
  const int n = num_nodes[b];
  const int t = threadIdx.x;
  const int wv = t >> 6, lane = t & 63;
  const int ln = lane & 15, q = lane >> 4;

  // ---- Phase B-stage: YT[b] -> LDS (issue loads early) ----
  for (int it = 0; it < 32; ++it) {
    const int id = t + it * 256;        // 8192 chunks of 8 shorts
    const int row = id >> 5, c8 = (id & 31) * 8;
    *(uint4*)&Ys[row][c8] = *(const uint4*)&YT[((size_t)b * 256 + row) * 256 + c8];
  }

  // ---- Phase A: masks ----
#pragma unroll 4
  for (int i = 0; i < 32; ++i) {
    const int k = wv * 32 + i;
    const int* arow = adj + ((size_t)b * GS + k) * GS;
    const unsigned long long m0 = __ballot(arow[lane] != 0);
    const unsigned long long m1 = __ballot(arow[64 + lane] != 0);
    if (lane == 0) {
      rm[k][0] = (uint32_t)m0; rm[k][1] = (uint32_t)(m0 >> 32);
      rm[k][2] = (uint32_t)m1; rm[k][3] = (uint32_t)(m1 >> 32);
    }
  }
  __syncthreads();
  if (t < 128) {
    uint32_t c0 = 0, c1 = 0, c2 = 0, c3 = 0;
    const int w = t >> 5, sh = t & 31;
#pragma unroll 8
    for (int k = 0; k < 128; ++k) {
      const uint32_t bit = (rm[k][w] >> sh) & 1u;
      if (k < 32)      c0 |= bit << k;
      else if (k < 64) c1 |= bit << (k - 32);
      else if (k < 96) c2 |= bit << (k - 64);
      else             c3 |= bit << (k - 96);
    }
    cmL[t][0] = c0; cmL[t][1] = c1; cmL[t][2] = c2; cmL[t][3] = c3;
  }
  __syncthreads();
  if (t == 0) {
    cmL[n][n >> 5] |= 1u << (n & 31);
    if (n > 0) {
      cmL[n - 1][n >> 5] |= 1u << (n & 31);
      cmL[n][(n - 1) >> 5] |= 1u << ((n - 1) & 31);
    }
  }
  __syncthreads();

  // ---- Phase B: MFMA P = [A^T | I] @ [Yrel;Yroot]^T-staged ----
  // wave wv owns h in [wv*64, wv*64+64); jt tiles cover j 0..127
  f32x4 acc[8][4] = {};
  for (int ks = 0; ks < 8; ++ks) {
    short8 bf[4];
#pragma unroll
    for (int ht = 0; ht < 4; ++ht)
      bf[ht] = *(const short8*)&Ys[wv * 64 + ht * 16 + ln][ks * 32 + q * 8];
#pragma unroll
    for (int jt = 0; jt < 8; ++jt) {
      short8 af;
      if (ks < 4) {
        const uint32_t w = cmL[jt * 16 + ln][ks];
        const uint32_t byte = (w >> (q * 8)) & 0xFFu;
#pragma unroll
        for (int i = 0; i < 8; ++i)
          af[i] = (short)(((byte >> i) & 1u) ? 0x3F80 : 0);
      } else {
        const int base = (ks - 4) * 32 + q * 8;   // k-128
        const int j = jt * 16 + ln;
#pragma unroll
        for (int i = 0; i < 8; ++i)
          af[i] = (short)((j == base + i) ? 0x3F80 : 0);
      }
#pragma unroll
      for (int ht = 0; ht < 4; ++ht)
        acc[jt][ht] = __builtin_amdgcn_mfma_f32_16x16x32_bf16(
            af, bf[ht], acc[jt][ht], 0, 0, 0);
    }
  }

  // ---- Phase C: epilogue: relu, masked sum over j in S, pick j==n ----
  const uint32_t S0 = cmL[n][0], S1 = cmL[n][1], S2 = cmL[n][2], S3 = cmL[n][3];
  float bb[4];
#pragma unroll
  for (int ht = 0; ht < 4; ++ht) bb[ht] = b0[wv * 64 + ht * 16 + ln];

  float asum[4] = {0.f, 0.f, 0.f, 0.f};
#pragma unroll
  for (int jt = 0; jt < 8; ++jt)
#pragma unroll
    for (int r = 0; r < 4; ++r) {
      const int j = jt * 16 + q * 4 + r;
      const uint32_t Sw = (j < 32) ? S0 : (j < 64) ? S1 : (j < 96) ? S2 : S3;
      const bool sj = (Sw >> (j & 31)) & 1u;
      const bool isn = (j == n);
#pragma unroll
      for (int ht = 0; ht < 4; ++ht) {
        const float v = fmaxf(bb[ht] + acc[jt][ht][r], 0.f);
        if (sj) asum[ht] += v;
        if (isn) h0n_s[wv * 64 + ht * 16 + ln] = v;
      }
    }
#pragma unroll
  for (int ht = 0; ht < 4; ++ht) redq[wv][q][ht * 16 + ln] = asum[ht];
  __syncthreads();
  {
    const int hl = t & 63, w2 = t >> 6;
    a1_s[t] = redq[w2][0][hl] + redq[w2][1][hl] + redq[w2][2][hl] + redq[w2][3][hl];
  }
  __syncthreads();

  // ---- Phase D: h1 = relu(a1 @ W1_rel + h0n @ W1_root + b1) ----
  {
    const int o4 = t * 4;
    float4 a = *(const float4*)&b1[o4];
#pragma unroll 8
    for (int h = 0; h < HSZ; ++h) {
      const float s = a1_s[h];
      const float4 w = *(const float4*)&W1_rel[(size_t)h * OUTSZ + o4];
      a.x = fmaf(s, w.x, a.x); a.y = fmaf(s, w.y, a.y);
      a.z = fmaf(s, w.z, a.z); a.w = fmaf(s, w.w, a.w);
    }
#pragma unroll 8
    for (int h = 0; h < HSZ; ++h) {
      const float s = h0n_s[h];
      const float4 w = *(const float4*)&W1_root[(size_t)h * OUTSZ + o4];
      a.x = fmaf(s, w.x, a.x); a.y = fmaf(s, w.y, a.y);
      a.z = fmaf(s, w.z, a.z); a.w = fmaf(s, w.w, a.w);
    }
    a.x = fmaxf(a.x, 0.f); a.y = fmaxf(a.y, 0.f);
    a.z = fmaxf(a.z, 0.f); a.w = fmaxf(a.w, 0.f);
    *(float4*)&h1[o4] = a;
  }
  __syncthreads();

  // ---- Phase E: head ----
  float p[19];
#pragma unroll
  for (int c = 0; c < 19; ++c) p[c] = 0.f;
#pragma unroll
  for (int i = 0; i < 4; ++i) {
    const int o = t + i * 256;
    const float v = h1[o];
#pragma unroll
    for (int c = 0; c < 19; ++c) p[c] = fmaf(v, WlT[(size_t)c * OUTSZ + o], p[c]);
  }
#pragma unroll
  for (int c = 0; c < 19; ++c) {
    float v = p[c];
    v += __shfl_down(v, 32); v += __shfl_down(v, 16);
    v += __shfl_down(v, 8);  v += __shfl_down(v, 4);
    v += __shfl_down(v, 2);  v += __shfl_down(v, 1);
    if (lane == 0) pl[c][wv] = v;
  }
  __syncthreads();
  if (t < 19) {
    const float s = pl[t][0] + pl[t][1] + pl[t][2] + pl[t][3];
    if (t < NOUT) out[(size_t)b * NOUT + t] = s + bl[t];
    else          out[(size_t)BATCH * NOUT + b] = s + bv[0];
  }
}

// ---------------------------------------------------------------------------
extern "C" void kernel_launch(void* const* d_in, const int* in_sizes, int n_in,
                              void* d_out, int out_size, void* d_ws, size_t ws_size,
                              hipStream_t stream)
{
  const float* flat      = (const float*)d_in[0];
  const float* nodes     = (const float*)d_in[1];
  const int*   num_nodes = (const int*)  d_in[2];
  const int*   adj       = (const int*)  d_in[3];
  const float* W0_rel    = (const float*)d_in[5];
  const float* b0        = (const float*)d_in[6];
  const float* W0_root   = (const float*)d_in[7];
  const float* W1_rel    = (const float*)d_in[8];
  const float* b1        = (const float*)d_in[9];
  const float* W1_root   = (const float*)d_in[10];
  const float* Wl        = (const float*)d_in[11];
  const float* bl        = (const float*)d_in[12];
  const float* Wv        = (const float*)d_in[13];
  const float* bv        = (const float*)d_in[14];
  float* out = (float*)d_out;

  char* ws = (char*)d_ws;
  ushort* YT  = (ushort*)ws;                 ws += (size_t)BATCH * 256 * 256 * 2; // 32 MiB
  ushort* Wt  = (ushort*)ws;                 ws += (size_t)512 * OBS * 2;         // 1 MiB
  float*  WlT = (float*)ws;                  ws += (size_t)19 * OUTSZ * 4;        // 76 KiB

  prep_wt<<<dim3(16, 8), 256, 0, stream>>>(W0_rel, W0_root, Wt);
  prep_wlt<<<1, 256, 0, stream>>>(Wl, Wv, WlT);
  gemm0_mfma<<<dim3(4, BATCH), 256, 0, stream>>>(
      flat, nodes, num_nodes, Wt, YT);
  fused_tail<<<BATCH, 256, 0, stream>>>(
      YT, adj, num_nodes, b0, W1_rel, W1_root, b1, WlT, bl, bv, out);
}